// Round 18
// baseline (265.449 us; speedup 1.0000x reference)
//
#include <hip/hip_runtime.h>
#include <hip/hip_bf16.h>
#include <stdint.h>

typedef unsigned short u16;
typedef unsigned int u32;
typedef unsigned long long u64;
typedef __attribute__((ext_vector_type(8))) short bf16x8;
typedef __attribute__((ext_vector_type(4))) float f32x4;

#define NB 2
#define NH 16
#define TT 2048
#define DD 64
#define CC 1024

__device__ __forceinline__ u16 bf16bits(float f) {
    __hip_bfloat16 h = __float2bfloat16(f);
    return __builtin_bit_cast(unsigned short, h);
}

__device__ __forceinline__ void gload_lds16(const void* g, void* l) {
    __builtin_amdgcn_global_load_lds(
        (const __attribute__((address_space(1))) void*)g,
        (__attribute__((address_space(3))) void*)l, 16, 0, 0);
}

// ---------------- fused prep: f32->bf16 converts + mask bit-pack -------------
__global__ __launch_bounds__(256) void prep_all(
    const float* __restrict__ x, const float* __restrict__ Wa_f,
    const float* __restrict__ Wp_f, const float* __restrict__ ml,
    u16* __restrict__ xb, u16* __restrict__ wab, u16* __restrict__ wpb,
    unsigned char* __restrict__ mb) {
    const int bid = blockIdx.x;
    if (bid < 512) {
        int idx = bid * 256 + threadIdx.x;
        for (int i = idx; i < 2097152; i += 512 * 256) {
            const float* src; u16* dst; int off;
            if (i < 1048576)      { src = x;    dst = xb;  off = i; }
            else if (i < 1835008) { src = Wa_f; dst = wab; off = i - 1048576; }
            else                  { src = Wp_f; dst = wpb; off = i - 1835008; }
            float4 v = reinterpret_cast<const float4*>(src)[off];
            ushort4 o;
            o.x = bf16bits(v.x); o.y = bf16bits(v.y);
            o.z = bf16bits(v.z); o.w = bf16bits(v.w);
            reinterpret_cast<ushort4*>(dst)[off] = o;
        }
    } else {
        const int wid = ((bid - 512) << 2) + (threadIdx.x >> 6);  // 0..4095
        const int lane = threadIdx.x & 63;
        const int i0 = wid & 2047;
        const int hbase = (wid >> 11) << 3;  // 0 or 8
#pragma unroll 1
        for (int k = 0; k < 8; ++k) {
            int h = hbase + k;
            int i = (k & 1) ? (2047 - i0) : i0;
            int row = h * 2048 + i;
            const float* src = ml + (size_t)row * TT;
            unsigned char* dst = mb + (size_t)row * (TT / 8);
            for (int c8 = lane; c8 * 8 <= i; c8 += 64) {
                const float4* p = reinterpret_cast<const float4*>(src + c8 * 8);
                float4 a = p[0];
                float4 b = p[1];
                unsigned v = 0;
                v |= (a.x > 0.f) ? 1u : 0u;
                v |= (a.y > 0.f) ? 2u : 0u;
                v |= (a.z > 0.f) ? 4u : 0u;
                v |= (a.w > 0.f) ? 8u : 0u;
                v |= (b.x > 0.f) ? 16u : 0u;
                v |= (b.y > 0.f) ? 32u : 0u;
                v |= (b.z > 0.f) ? 64u : 0u;
                v |= (b.w > 0.f) ? 128u : 0u;
                dst[c8] = (unsigned char)v;
            }
        }
    }
}

// ---------------- GEMM: C[m,n] = sum_k A[m,k]*Bw[n,k] + bias[n] ----------------
template <int MODE>
__global__ __launch_bounds__(256) void gemm_bt(
    const u16* __restrict__ A, const u16* __restrict__ Bw,
    const float* __restrict__ bias,
    u16* __restrict__ Qb, u16* __restrict__ Kb, u16* __restrict__ Vtb,
    float* __restrict__ Cout, int Kdim) {
    const int bm = blockIdx.y * 128;
    const int bn = blockIdx.x * 128;
    const int tid = threadIdx.x;
    const int w = tid >> 6, lane = tid & 63;
    const int lrow = lane & 15, lgrp = lane >> 4;
    const int wr = (w >> 1) * 64, wc = (w & 1) * 64;

    __shared__ __align__(16) u16 ABs[2][128 * 64];
    u16* As = ABs[0];
    u16* Bs = ABs[1];

    f32x4 acc[4][4] = {};

    const int nkt = Kdim >> 6;
    for (int kt = 0; kt < nkt; ++kt) {
        const int k0 = kt << 6;
#pragma unroll
        for (int i = 0; i < 4; ++i) {
            int e = i * 2048 + tid * 8;
            int r = e >> 6, c = e & 63;
            gload_lds16(A + (size_t)(bm + r) * Kdim + k0 + c, (char*)As + i * 4096 + w * 1024);
            gload_lds16(Bw + (size_t)(bn + r) * Kdim + k0 + c, (char*)Bs + i * 4096 + w * 1024);
        }
        __syncthreads();
#pragma unroll
        for (int kk = 0; kk < 2; ++kk) {
            bf16x8 af[4], bfz[4];
#pragma unroll
            for (int i = 0; i < 4; ++i)
                af[i] = *reinterpret_cast<const bf16x8*>(&As[(wr + i * 16 + lrow) * 64 + kk * 32 + lgrp * 8]);
#pragma unroll
            for (int i = 0; i < 4; ++i)
                bfz[i] = *reinterpret_cast<const bf16x8*>(&Bs[(wc + i * 16 + lrow) * 64 + kk * 32 + lgrp * 8]);
#pragma unroll
            for (int mi = 0; mi < 4; ++mi)
#pragma unroll
                for (int ni = 0; ni < 4; ++ni)
                    acc[mi][ni] = __builtin_amdgcn_mfma_f32_16x16x32_bf16(af[mi], bfz[ni], acc[mi][ni], 0, 0, 0);
        }
        __syncthreads();
    }

    const int sec = (MODE == 0) ? (bn >> 10) : 1;

    if (MODE == 0 && sec == 2) {
        // ---- V epilogue: LDS transpose for coalesced Vt writes ----
        u16* Tl = &ABs[0][0];
#pragma unroll
        for (int ni = 0; ni < 4; ++ni) {
            int nl = wc + ni * 16 + lrow;
            float bv = bias[bn + nl];
#pragma unroll
            for (int mi = 0; mi < 4; ++mi) {
                int ml2 = wr + mi * 16 + lgrp * 4;
                u64 pk = 0;
#pragma unroll
                for (int j = 0; j < 4; ++j)
                    pk |= (u64)bf16bits(acc[mi][ni][j] + bv) << (16 * j);
                int byte = nl * 256 + ((ml2 * 2) ^ ((nl & 7) << 4));
                *reinterpret_cast<u64*>((char*)Tl + byte) = pk;
            }
        }
        __syncthreads();
        int r = tid >> 1, half = tid & 1;
        int h = ((bn & 1023) >> 6) + (r >> 6);
        int d = r & 63;
        int b = bm >> 11;
        u16* gdst = Vtb + (((size_t)b * NH + h) * DD + d) * TT + (bm & 2047) + half * 64;
#pragma unroll
        for (int c = 0; c < 8; ++c) {
            uint4 v = *reinterpret_cast<const uint4*>(
                (char*)Tl + r * 256 + ((half * 128 + c * 16) ^ ((r & 7) << 4)));
            *reinterpret_cast<uint4*>(gdst + c * 8) = v;
        }
        return;
    }

#pragma unroll
    for (int ni = 0; ni < 4; ++ni) {
        int n = bn + wc + ni * 16 + lrow;
        float bv = bias[n];
#pragma unroll
        for (int mi = 0; mi < 4; ++mi) {
#pragma unroll
            for (int j = 0; j < 4; ++j) {
                int m = bm + wr + mi * 16 + lgrp * 4 + j;
                float v = acc[mi][ni][j] + bv;
                if (MODE == 1) {
                    Cout[(size_t)m * 1024 + n] = v;
                } else {
                    int h = (n & 1023) >> 6;
                    int d = n & 63;
                    int b = m >> 11;
                    int t = m & 2047;
                    if (sec == 0) {
                        // fold 1/sqrt(64) and log2(e): softmax runs in exp2 domain
                        Qb[(((size_t)b * NH + h) * TT + t) * DD + d] =
                            bf16bits(v * (0.125f * 1.4426950408889634f));
                    } else {
                        Kb[(((size_t)b * NH + h) * TT + t) * DD + d] = bf16bits(v);
                    }
                }
            }
        }
    }
}

// ---------------- fused masked flash attention, barrier-free -----------------
// K/V are L2-resident (2MB/XCD under bid&7=h&7 mapping) -> read fragments
// DIRECTLY from global into registers; no K/V LDS staging, no double-buffer,
// and since the only LDS (Ps) is wave-private: ZERO barriers in the k-loop.
// Waves run free; latency hidden by TLP (12-16 waves/CU), not lockstep.
// grid: (512 = slot*16+h, 2 batches); block 256 = 4 waves, one 64-row q-tile.
__global__ __launch_bounds__(256) void attn_kernel(
    const u16* __restrict__ Qb, const u16* __restrict__ Kb,
    const u16* __restrict__ Vtb, const unsigned char* __restrict__ mb,
    u16* __restrict__ att_out) {
    const int slot = blockIdx.x >> 4;
    const int h = blockIdx.x & 15;
    const int b = blockIdx.y;
    const int qt = (slot < 16) ? (31 - slot) : (slot - 16);
    const int tid = threadIdx.x;
    const int w = tid >> 6, lane = tid & 63;
    const int lrow = lane & 15, g = lane >> 4;

    __shared__ __align__(16) u16 Ps[4][16 * 64];  // wave-private, XOR-swizzled

    const u16* kg = &Kb[((size_t)b * NH + h) * TT * DD];   // [t][d]
    const u16* vg = &Vtb[((size_t)b * NH + h) * DD * TT];  // [d][t]

    const int qrow_g = qt * 64 + w * 16 + lrow;  // this lane's softmax row
    const int rswz = (lrow & 7) << 4;            // Ps byte swizzle

    bf16x8 qf[2];
#pragma unroll
    for (int kk = 0; kk < 2; ++kk)
        qf[kk] = *reinterpret_cast<const bf16x8*>(
            &Qb[(((size_t)b * NH + h) * TT + qrow_g) * DD + kk * 32 + g * 8]);

    f32x4 oacc[4] = {};          // O[qr = g*4+j][d = dt*16+lrow]
    float l_run = 0.f;

    const unsigned char* mrow_base = mb + ((size_t)h * TT + qrow_g) * (TT / 8);
    char* PsW = (char*)&Ps[w][0];

    // per-lane fragment base pointers
    const u16* kbase = kg + (size_t)lrow * DD + g * 8;  // + (kt*64+nt*16)*DD + kk*32
    const u16* vbase = vg + (size_t)lrow * TT + g * 8;  // + dt*16*TT + kt*64 + kk*32

#pragma unroll 1
    for (int kt = 0; kt <= qt; ++kt) {
        u64 mw = *reinterpret_cast<const u64*>(mrow_base + kt * 8);

        // ---- K fragments: direct global (L2) loads ----
        bf16x8 kf[8];
#pragma unroll
        for (int kk = 0; kk < 2; ++kk)
#pragma unroll
            for (int nt = 0; nt < 4; ++nt)
                kf[kk * 4 + nt] = *reinterpret_cast<const bf16x8*>(
                    kbase + (size_t)(kt * 64 + nt * 16) * DD + kk * 32);

        // ---- S^T = K Q^T (exp2 domain): lane holds S[qrow_g][16 cols] ----
        f32x4 s[4] = {};
        __builtin_amdgcn_s_setprio(1);
#pragma unroll
        for (int kk = 0; kk < 2; ++kk)
#pragma unroll
            for (int nt = 0; nt < 4; ++nt)
                s[nt] = __builtin_amdgcn_mfma_f32_16x16x32_bf16(kf[kk * 4 + nt], qf[kk], s[nt], 0, 0, 0);
        __builtin_amdgcn_s_setprio(0);

        // ---- V fragments issued now; softmax covers their latency ----
        bf16x8 vv[8];
#pragma unroll
        for (int kk = 0; kk < 2; ++kk)
#pragma unroll
            for (int dt = 0; dt < 4; ++dt)
                vv[kk * 4 + dt] = *reinterpret_cast<const bf16x8*>(
                    vbase + (size_t)(dt * 16) * TT + kt * 64 + kk * 32);

        // ---- P = keep ? exp2(S) : 0   (static max; pre-shifted mask word) ----
        u64 mws = mw >> (g * 4);
        u32 mlo = (u32)mws, mhi = (u32)(mws >> 32);
        float rs = 0.f;
        if (kt == qt) {
#pragma unroll
            for (int nt = 0; nt < 4; ++nt)
#pragma unroll
                for (int j = 0; j < 4; ++j) {
                    int bi = nt * 16 + j;
                    bool keep = (((bi < 32 ? mlo : mhi) >> (bi & 31)) & 1) &&
                                (kt * 64 + nt * 16 + g * 4 + j <= qrow_g);
                    float p = keep ? exp2f(s[nt][j]) : 0.f;
                    rs += p;
                    s[nt][j] = p;
                }
        } else {
#pragma unroll
            for (int nt = 0; nt < 4; ++nt)
#pragma unroll
                for (int j = 0; j < 4; ++j) {
                    int bi = nt * 16 + j;
                    bool keep = ((bi < 32 ? mlo : mhi) >> (bi & 31)) & 1;
                    float p = keep ? exp2f(s[nt][j]) : 0.f;
                    rs += p;
                    s[nt][j] = p;
                }
        }
        rs += __shfl_xor(rs, 16);
        rs += __shfl_xor(rs, 32);
        l_run += rs;

        // ---- pack P -> wave-private swizzled LDS (no cross-wave sync) ----
#pragma unroll
        for (int nt = 0; nt < 4; ++nt)
#pragma unroll
            for (int t = 0; t < 2; ++t) {
                u32 pk = (u32)bf16bits(s[nt][2 * t]) |
                         ((u32)bf16bits(s[nt][2 * t + 1]) << 16);
                int byte = (lrow * 128 + (nt * 16 + g * 4 + 2 * t) * 2) ^ rswz;
                *reinterpret_cast<u32*>(PsW + byte) = pk;
            }

        // ---- O += P @ V (V from registers) ----
        __builtin_amdgcn_s_setprio(1);
#pragma unroll
        for (int kk = 0; kk < 2; ++kk) {
            bf16x8 pf = *reinterpret_cast<const bf16x8*>(
                PsW + ((lrow * 128 + (kk * 32 + g * 8) * 2) ^ rswz));
#pragma unroll
            for (int dt = 0; dt < 4; ++dt)
                oacc[dt] = __builtin_amdgcn_mfma_f32_16x16x32_bf16(pf, vv[kk * 4 + dt], oacc[dt], 0, 0, 0);
        }
        __builtin_amdgcn_s_setprio(0);
    }

    // ---- epilogue: normalize + store bf16 [B,T,C] ----
    float lb[4];
#pragma unroll
    for (int j = 0; j < 4; ++j)
        lb[j] = __shfl(l_run, (lane & 48) + g * 4 + j);
#pragma unroll
    for (int dt = 0; dt < 4; ++dt)
#pragma unroll
        for (int j = 0; j < 4; ++j) {
            int t = qt * 64 + w * 16 + g * 4 + j;
            float o = oacc[dt][j] / lb[j];
            att_out[((size_t)b * TT + t) * CC + h * DD + dt * 16 + lrow] = bf16bits(o);
        }
}

extern "C" void kernel_launch(void* const* d_in, const int* in_sizes, int n_in,
                              void* d_out, int out_size, void* d_ws, size_t ws_size,
                              hipStream_t stream) {
    const float* x = (const float*)d_in[0];
    const float* mask_logits = (const float*)d_in[1];
    const float* W_attn = (const float*)d_in[2];
    const float* b_attn = (const float*)d_in[3];
    const float* W_proj = (const float*)d_in[4];
    const float* b_proj = (const float*)d_in[5];
    float* out = (float*)d_out;

    char* ws = (char*)d_ws;
    u16* xb  = (u16*)(ws + 0);            // 8 MB — dead after QKV gemm
    u16* Wa  = (u16*)(ws + (8u << 20));   // 6 MB
    u16* Wp  = (u16*)(ws + (14u << 20));  // 2 MB
    u16* Qb  = (u16*)(ws + (16u << 20));  // 8 MB  [B,H,T,D]
    u16* Kb  = (u16*)(ws + (24u << 20));  // 8 MB  [B,H,T,D]
    u16* Vtb = (u16*)(ws + (32u << 20));  // 8 MB  [B,H,D,T]
    u16* att = (u16*)(ws + (40u << 20));  // 8 MB  [B,T,C]
    unsigned char* mbits = (unsigned char*)(ws + (48u << 20));  // 8 MB

    prep_all<<<1536, 256, 0, stream>>>(x, W_attn, W_proj, mask_logits,
                                       xb, Wa, Wp, mbits);
    gemm_bt<0><<<dim3(24, 32), 256, 0, stream>>>(xb, Wa, b_attn, Qb, Kb, Vtb, nullptr, CC);
    attn_kernel<<<dim3(512, 2), 256, 0, stream>>>(Qb, Kb, Vtb, mbits, att);
    gemm_bt<1><<<dim3(8, 32), 256, 0, stream>>>(att, Wp, b_proj, nullptr, nullptr, nullptr, out, CC);
}

// Round 19
// 161.376 us; speedup vs baseline: 1.6449x; 1.6449x over previous
//
#include <hip/hip_runtime.h>
#include <hip/hip_bf16.h>
#include <stdint.h>

typedef unsigned short u16;
typedef unsigned int u32;
typedef unsigned long long u64;
typedef __attribute__((ext_vector_type(8))) short bf16x8;
typedef __attribute__((ext_vector_type(4))) float f32x4;

#define NB 2
#define NH 16
#define TT 2048
#define DD 64
#define CC 1024

__device__ __forceinline__ u16 bf16bits(float f) {
    __hip_bfloat16 h = __float2bfloat16(f);
    return __builtin_bit_cast(unsigned short, h);
}

__device__ __forceinline__ void gload_lds16(const void* g, void* l) {
    __builtin_amdgcn_global_load_lds(
        (const __attribute__((address_space(1))) void*)g,
        (__attribute__((address_space(3))) void*)l, 16, 0, 0);
}

// ---------------- fused prep: f32->bf16 converts + causal-clipped mask bits --
// Mask rows are written FULL (256B/row) with bits past column i zeroed ->
// the attention kernel needs zero causal logic.
__global__ __launch_bounds__(256) void prep_all(
    const float* __restrict__ x, const float* __restrict__ Wa_f,
    const float* __restrict__ Wp_f, const float* __restrict__ ml,
    u16* __restrict__ xb, u16* __restrict__ wab, u16* __restrict__ wpb,
    unsigned char* __restrict__ mb) {
    const int bid = blockIdx.x;
    if (bid < 512) {
        int idx = bid * 256 + threadIdx.x;
        for (int i = idx; i < 2097152; i += 512 * 256) {
            const float* src; u16* dst; int off;
            if (i < 1048576)      { src = x;    dst = xb;  off = i; }
            else if (i < 1835008) { src = Wa_f; dst = wab; off = i - 1048576; }
            else                  { src = Wp_f; dst = wpb; off = i - 1835008; }
            float4 v = reinterpret_cast<const float4*>(src)[off];
            ushort4 o;
            o.x = bf16bits(v.x); o.y = bf16bits(v.y);
            o.z = bf16bits(v.z); o.w = bf16bits(v.w);
            reinterpret_cast<ushort4*>(dst)[off] = o;
        }
    } else {
        const int wid = ((bid - 512) << 2) + (threadIdx.x >> 6);  // 0..4095
        const int lane = threadIdx.x & 63;
        const int i0 = wid & 2047;
        const int hbase = (wid >> 11) << 3;  // 0 or 8
#pragma unroll 1
        for (int k = 0; k < 8; ++k) {
            int h = hbase + k;
            int i = (k & 1) ? (2047 - i0) : i0;
            int row = h * 2048 + i;
            const float* src = ml + (size_t)row * TT;
            unsigned char* dst = mb + (size_t)row * (TT / 8);
#pragma unroll 1
            for (int c8 = lane; c8 < 256; c8 += 64) {
                unsigned char v = 0;
                if (c8 * 8 <= i) {
                    const float4* p = reinterpret_cast<const float4*>(src + c8 * 8);
                    float4 a = p[0];
                    float4 b = p[1];
                    unsigned u = 0;
                    u |= (a.x > 0.f) ? 1u : 0u;
                    u |= (a.y > 0.f) ? 2u : 0u;
                    u |= (a.z > 0.f) ? 4u : 0u;
                    u |= (a.w > 0.f) ? 8u : 0u;
                    u |= (b.x > 0.f) ? 16u : 0u;
                    u |= (b.y > 0.f) ? 32u : 0u;
                    u |= (b.z > 0.f) ? 64u : 0u;
                    u |= (b.w > 0.f) ? 128u : 0u;
                    int rem = i - c8 * 8;
                    if (rem < 7) u &= (1u << (rem + 1)) - 1;  // causal clip
                    v = (unsigned char)u;
                }
                dst[c8] = v;
            }
        }
    }
}

// ---------------- GEMM: C[m,n] = sum_k A[m,k]*Bw[n,k] + bias[n] ----------------
template <int MODE>
__global__ __launch_bounds__(256) void gemm_bt(
    const u16* __restrict__ A, const u16* __restrict__ Bw,
    const float* __restrict__ bias,
    u16* __restrict__ Qb, u16* __restrict__ Kb, u16* __restrict__ Vtb,
    float* __restrict__ Cout, int Kdim) {
    const int bm = blockIdx.y * 128;
    const int bn = blockIdx.x * 128;
    const int tid = threadIdx.x;
    const int w = tid >> 6, lane = tid & 63;
    const int lrow = lane & 15, lgrp = lane >> 4;
    const int wr = (w >> 1) * 64, wc = (w & 1) * 64;

    __shared__ __align__(16) u16 ABs[2][128 * 64];
    u16* As = ABs[0];
    u16* Bs = ABs[1];

    f32x4 acc[4][4] = {};

    const int nkt = Kdim >> 6;
    for (int kt = 0; kt < nkt; ++kt) {
        const int k0 = kt << 6;
#pragma unroll
        for (int i = 0; i < 4; ++i) {
            int e = i * 2048 + tid * 8;
            int r = e >> 6, c = e & 63;
            gload_lds16(A + (size_t)(bm + r) * Kdim + k0 + c, (char*)As + i * 4096 + w * 1024);
            gload_lds16(Bw + (size_t)(bn + r) * Kdim + k0 + c, (char*)Bs + i * 4096 + w * 1024);
        }
        __syncthreads();
#pragma unroll
        for (int kk = 0; kk < 2; ++kk) {
            bf16x8 af[4], bfz[4];
#pragma unroll
            for (int i = 0; i < 4; ++i)
                af[i] = *reinterpret_cast<const bf16x8*>(&As[(wr + i * 16 + lrow) * 64 + kk * 32 + lgrp * 8]);
#pragma unroll
            for (int i = 0; i < 4; ++i)
                bfz[i] = *reinterpret_cast<const bf16x8*>(&Bs[(wc + i * 16 + lrow) * 64 + kk * 32 + lgrp * 8]);
#pragma unroll
            for (int mi = 0; mi < 4; ++mi)
#pragma unroll
                for (int ni = 0; ni < 4; ++ni)
                    acc[mi][ni] = __builtin_amdgcn_mfma_f32_16x16x32_bf16(af[mi], bfz[ni], acc[mi][ni], 0, 0, 0);
        }
        __syncthreads();
    }

    const int sec = (MODE == 0) ? (bn >> 10) : 1;

    if (MODE == 0 && sec == 2) {
        // ---- V epilogue: LDS transpose for coalesced Vt writes ----
        u16* Tl = &ABs[0][0];
#pragma unroll
        for (int ni = 0; ni < 4; ++ni) {
            int nl = wc + ni * 16 + lrow;
            float bv = bias[bn + nl];
#pragma unroll
            for (int mi = 0; mi < 4; ++mi) {
                int ml2 = wr + mi * 16 + lgrp * 4;
                u64 pk = 0;
#pragma unroll
                for (int j = 0; j < 4; ++j)
                    pk |= (u64)bf16bits(acc[mi][ni][j] + bv) << (16 * j);
                int byte = nl * 256 + ((ml2 * 2) ^ ((nl & 7) << 4));
                *reinterpret_cast<u64*>((char*)Tl + byte) = pk;
            }
        }
        __syncthreads();
        int r = tid >> 1, half = tid & 1;
        int h = ((bn & 1023) >> 6) + (r >> 6);
        int d = r & 63;
        int b = bm >> 11;
        u16* gdst = Vtb + (((size_t)b * NH + h) * DD + d) * TT + (bm & 2047) + half * 64;
#pragma unroll
        for (int c = 0; c < 8; ++c) {
            uint4 v = *reinterpret_cast<const uint4*>(
                (char*)Tl + r * 256 + ((half * 128 + c * 16) ^ ((r & 7) << 4)));
            *reinterpret_cast<uint4*>(gdst + c * 8) = v;
        }
        return;
    }

#pragma unroll
    for (int ni = 0; ni < 4; ++ni) {
        int n = bn + wc + ni * 16 + lrow;
        float bv = bias[n];
#pragma unroll
        for (int mi = 0; mi < 4; ++mi) {
#pragma unroll
            for (int j = 0; j < 4; ++j) {
                int m = bm + wr + mi * 16 + lgrp * 4 + j;
                float v = acc[mi][ni][j] + bv;
                if (MODE == 1) {
                    Cout[(size_t)m * 1024 + n] = v;
                } else {
                    int h = (n & 1023) >> 6;
                    int d = n & 63;
                    int b = m >> 11;
                    int t = m & 2047;
                    if (sec == 0) {
                        // fold 1/sqrt(64) and log2(e): softmax runs in exp2 domain
                        Qb[(((size_t)b * NH + h) * TT + t) * DD + d] =
                            bf16bits(v * (0.125f * 1.4426950408889634f));
                    } else {
                        Kb[(((size_t)b * NH + h) * TT + t) * DD + d] = bf16bits(v);
                    }
                }
            }
        }
    }
}

// ---------------- fused masked flash attention (r16 structure) ---------------
// Causal clip is pre-baked into the mask bits -> single uniform tile path.
// Branchless keep: sign-extend bit (v_bfe_i32) AND'd into exp2 result.
// grid: (512 = slot*16+h, 2 batches); block 256 = 4 waves, one 64-row q-tile.
__global__ __launch_bounds__(256) void attn_kernel(
    const u16* __restrict__ Qb, const u16* __restrict__ Kb,
    const u16* __restrict__ Vtb, const unsigned char* __restrict__ mb,
    u16* __restrict__ att_out) {
    const int slot = blockIdx.x >> 4;
    const int h = blockIdx.x & 15;
    const int b = blockIdx.y;
    const int qt = (slot < 16) ? (31 - slot) : (slot - 16);
    const int tid = threadIdx.x;
    const int w = tid >> 6, lane = tid & 63;
    const int lrow = lane & 15, g = lane >> 4;

    __shared__ __align__(16) u16 Ks[2][64 * 64];
    __shared__ __align__(16) u16 Vts[2][64 * 64];
    __shared__ __align__(16) u16 Ps[4][16 * 64];  // per-wave, XOR-swizzled

    const u16* kg_base = &Kb[((size_t)b * NH + h) * TT * DD];
    const u16* vg_base = &Vtb[((size_t)b * NH + h) * DD * TT];

    auto STAGE = [&](int bufi, int kt) {
#pragma unroll
        for (int i = 0; i < 2; ++i) {
            int e = i * 2048 + tid * 8;
            int r = e >> 6, c = e & 63;
            int cs = c ^ ((r & 7) << 3);  // u16 units, keeps 16B alignment
            gload_lds16(kg_base + (size_t)kt * 64 * DD + r * DD + cs,
                        (char*)Ks[bufi] + i * 4096 + w * 1024);
            gload_lds16(vg_base + kt * 64 + (size_t)r * TT + cs,
                        (char*)Vts[bufi] + i * 4096 + w * 1024);
        }
    };

    const int qrow_g = qt * 64 + w * 16 + lrow;  // this lane's softmax row
    const int rswz = (lrow & 7) << 4;            // read-side byte swizzle

    bf16x8 qf[2];
#pragma unroll
    for (int kk = 0; kk < 2; ++kk)
        qf[kk] = *reinterpret_cast<const bf16x8*>(
            &Qb[(((size_t)b * NH + h) * TT + qrow_g) * DD + kk * 32 + g * 8]);

    f32x4 oacc[4] = {};          // O[qr = g*4+j][d = dt*16+lrow]
    float l_run = 0.f;

    const unsigned char* mrow_base = mb + ((size_t)h * TT + qrow_g) * (TT / 8);
    char* PsW = (char*)&Ps[w][0];

    STAGE(0, 0);
    int buf = 0;

#pragma unroll 1
    for (int kt = 0; kt <= qt; ++kt) {
        u64 mw = *reinterpret_cast<const u64*>(mrow_base + kt * 8);
        // counted vmcnt: wait only this tile's 4 staging loads; next tile's
        // 4 staging loads + the mask load remain in flight.
        if (kt < qt) {
            STAGE(buf ^ 1, kt + 1);
            asm volatile("s_waitcnt vmcnt(5)" ::: "memory");
        } else {
            asm volatile("s_waitcnt vmcnt(1)" ::: "memory");
        }
        __builtin_amdgcn_sched_barrier(0);
        asm volatile("s_barrier" ::: "memory");

        // ---- S^T = K Q^T (exp2 domain): lane holds S[qrow_g][16 cols] ----
        f32x4 s[4] = {};
        __builtin_amdgcn_s_setprio(1);
#pragma unroll
        for (int kk = 0; kk < 2; ++kk)
#pragma unroll
            for (int nt = 0; nt < 4; ++nt) {
                bf16x8 kf = *reinterpret_cast<const bf16x8*>(
                    (char*)Ks[buf] + (((nt * 16 + lrow) * 128 + (kk * 32 + g * 8) * 2) ^ rswz));
                s[nt] = __builtin_amdgcn_mfma_f32_16x16x32_bf16(kf, qf[kk], s[nt], 0, 0, 0);
            }
        __builtin_amdgcn_s_setprio(0);

        // ---- P = exp2(S) & signext(maskbit)  (uniform path; causal pre-baked)
        u64 mws = mw >> (g * 4);
        u32 wlo = (u32)mws, whi = (u32)(mws >> 32);
        float rs = 0.f;
#pragma unroll
        for (int nt = 0; nt < 4; ++nt)
#pragma unroll
            for (int j = 0; j < 4; ++j) {
                int bi = nt * 16 + j;
                u32 word = (bi < 32) ? wlo : whi;
                u32 pm = (u32)(((int)(word << (31 - (bi & 31)))) >> 31);  // 0 / ~0
                float p = __builtin_bit_cast(float,
                          __builtin_bit_cast(u32, exp2f(s[nt][j])) & pm);
                rs += p;
                s[nt][j] = p;
            }
        rs += __shfl_xor(rs, 16);
        rs += __shfl_xor(rs, 32);
        l_run += rs;

        // ---- pack P -> swizzled LDS (8x ds_write_b32) ----
#pragma unroll
        for (int nt = 0; nt < 4; ++nt)
#pragma unroll
            for (int t = 0; t < 2; ++t) {
                u32 pk = (u32)bf16bits(s[nt][2 * t]) |
                         ((u32)bf16bits(s[nt][2 * t + 1]) << 16);
                int byte = (lrow * 128 + (nt * 16 + g * 4 + 2 * t) * 2) ^ rswz;
                *reinterpret_cast<u32*>(PsW + byte) = pk;
            }

        // ---- O += P @ V ----
        __builtin_amdgcn_s_setprio(1);
#pragma unroll
        for (int kk = 0; kk < 2; ++kk) {
            bf16x8 pf = *reinterpret_cast<const bf16x8*>(
                PsW + ((lrow * 128 + (kk * 32 + g * 8) * 2) ^ rswz));
#pragma unroll
            for (int dt = 0; dt < 4; ++dt) {
                bf16x8 vf = *reinterpret_cast<const bf16x8*>(
                    (char*)Vts[buf] + (((dt * 16 + lrow) * 128 + (kk * 32 + g * 8) * 2) ^ rswz));
                oacc[dt] = __builtin_amdgcn_mfma_f32_16x16x32_bf16(pf, vf, oacc[dt], 0, 0, 0);
            }
        }
        __builtin_amdgcn_s_setprio(0);

        // protect buf for next iteration's STAGE (no vmcnt drain)
        asm volatile("s_barrier" ::: "memory");
        buf ^= 1;
    }

    // ---- epilogue: normalize + store bf16 [B,T,C] ----
    float lb[4];
#pragma unroll
    for (int j = 0; j < 4; ++j)
        lb[j] = __shfl(l_run, (lane & 48) + g * 4 + j);
#pragma unroll
    for (int dt = 0; dt < 4; ++dt)
#pragma unroll
        for (int j = 0; j < 4; ++j) {
            int t = qt * 64 + w * 16 + g * 4 + j;
            float o = oacc[dt][j] / lb[j];
            att_out[((size_t)b * TT + t) * CC + h * DD + dt * 16 + lrow] = bf16bits(o);
        }
}

extern "C" void kernel_launch(void* const* d_in, const int* in_sizes, int n_in,
                              void* d_out, int out_size, void* d_ws, size_t ws_size,
                              hipStream_t stream) {
    const float* x = (const float*)d_in[0];
    const float* mask_logits = (const float*)d_in[1];
    const float* W_attn = (const float*)d_in[2];
    const float* b_attn = (const float*)d_in[3];
    const float* W_proj = (const float*)d_in[4];
    const float* b_proj = (const float*)d_in[5];
    float* out = (float*)d_out;

    char* ws = (char*)d_ws;
    u16* xb  = (u16*)(ws + 0);            // 8 MB — dead after QKV gemm
    u16* Wa  = (u16*)(ws + (8u << 20));   // 6 MB
    u16* Wp  = (u16*)(ws + (14u << 20));  // 2 MB
    u16* Qb  = (u16*)(ws + (16u << 20));  // 8 MB  [B,H,T,D]
    u16* Kb  = (u16*)(ws + (24u << 20));  // 8 MB  [B,H,T,D]
    u16* Vtb = (u16*)(ws + (32u << 20));  // 8 MB  [B,H,D,T]
    u16* att = (u16*)(ws + (40u << 20));  // 8 MB  [B,T,C]
    unsigned char* mbits = (unsigned char*)(ws + (48u << 20));  // 8 MB

    prep_all<<<1536, 256, 0, stream>>>(x, W_attn, W_proj, mask_logits,
                                       xb, Wa, Wp, mbits);
    gemm_bt<0><<<dim3(24, 32), 256, 0, stream>>>(xb, Wa, b_attn, Qb, Kb, Vtb, nullptr, CC);
    attn_kernel<<<dim3(512, 2), 256, 0, stream>>>(Qb, Kb, Vtb, mbits, att);
    gemm_bt<1><<<dim3(8, 32), 256, 0, stream>>>(att, Wp, b_proj, nullptr, nullptr, nullptr, out, CC);
}